// Round 9
// baseline (264.369 us; speedup 1.0000x reference)
//
#include <hip/hip_runtime.h>

typedef unsigned short u16;
typedef __bf16 bf16x8 __attribute__((ext_vector_type(8)));
typedef float f32x4 __attribute__((ext_vector_type(4)));

// ---- problem constants ----
constexpr int SEQ = 2048;
constexpr int HIDN = 2880;
constexpr int NQKV = 5120;   // 4096 q | 512 k | 512 v
constexpr float SCALE = 0.125f;   // 1/sqrt(64)
constexpr float NEG_INF = -1e30f;

__device__ __forceinline__ u16 f2bf(float f) {
  unsigned int u = __builtin_bit_cast(unsigned int, f);
  u += 0x7FFFu + ((u >> 16) & 1u);
  return (u16)(u >> 16);
}
__device__ __forceinline__ float bf2f(u16 h) {
  unsigned int u = ((unsigned int)h) << 16;
  return __builtin_bit_cast(float, u);
}
__device__ __forceinline__ void async_load16(const void* g, void* l) {
  __builtin_amdgcn_global_load_lds(
      (const __attribute__((address_space(1))) unsigned int*)g,
      (__attribute__((address_space(3))) unsigned int*)l, 16, 0, 0);
}

// ---- fp32 -> bf16 flat convert ----
__global__ __launch_bounds__(256) void conv_f2b(const float* __restrict__ in,
                                                u16* __restrict__ out, long n4) {
  long i = (long)blockIdx.x * 256 + threadIdx.x;
  if (i >= n4) return;
  float4 v = ((const float4*)in)[i];
  u16 o0 = f2bf(v.x), o1 = f2bf(v.y), o2 = f2bf(v.z), o3 = f2bf(v.w);
  out[i * 4 + 0] = o0; out[i * 4 + 1] = o1; out[i * 4 + 2] = o2; out[i * 4 + 3] = o3;
}

// ---- merged Wq|Wk|Wv transpose-convert -> Wqkv[5120][2880] bf16 ----
__global__ __launch_bounds__(256) void transpose_qkv(const float* __restrict__ Wq,
                                                     const float* __restrict__ Wk,
                                                     const float* __restrict__ Wv,
                                                     u16* __restrict__ out) {
  __shared__ float tile[32][33];
  int c0 = blockIdx.x * 32, r0 = blockIdx.y * 32;   // c0: qkv col, r0: hid row
  int tx = threadIdx.x & 31, ty = threadIdx.x >> 5;
  const float* src; int C, cl;
  if (c0 < 4096)      { src = Wq; C = 4096; cl = c0; }
  else if (c0 < 4608) { src = Wk; C = 512;  cl = c0 - 4096; }
  else                { src = Wv; C = 512;  cl = c0 - 4608; }
#pragma unroll
  for (int i = 0; i < 32; i += 8)
    tile[ty + i][tx] = src[(long)(r0 + ty + i) * C + cl + tx];
  __syncthreads();
#pragma unroll
  for (int i = 0; i < 32; i += 8)
    out[(long)(c0 + ty + i) * HIDN + r0 + tx] = f2bf(tile[tx][ty + i]);
}

// ---- fp32 [R][C] -> bf16 out[c][r] (transpose-convert), dims % 32 == 0 ----
__global__ __launch_bounds__(256) void transpose_f2b(const float* __restrict__ in,
                                                     u16* __restrict__ out,
                                                     int R, int C, int ostride) {
  __shared__ float tile[32][33];
  int c0 = blockIdx.x * 32, r0 = blockIdx.y * 32;
  int tx = threadIdx.x & 31, ty = threadIdx.x >> 5;
#pragma unroll
  for (int i = 0; i < 32; i += 8)
    tile[ty + i][tx] = in[(long)(r0 + ty + i) * C + c0 + tx];
  __syncthreads();
#pragma unroll
  for (int i = 0; i < 32; i += 8)
    out[(long)(c0 + ty + i) * ostride + r0 + tx] = f2bf(tile[tx][ty + i]);
}

__global__ __launch_bounds__(256) void concat_bias(const float* bq, const float* bk,
                                                   const float* bv, float* out) {
  int t = blockIdx.x * 256 + threadIdx.x;
  if (t < 4096) out[t] = bq[t];
  else if (t < 4608) out[t] = bk[t - 4096];
  else if (t < 5120) out[t] = bv[t - 4608];
}

// ======== GEMM: C[M][N] = A[M][K] @ B_t[N][K]^T ========
// m97-style structure, maximized block TLP. BM=BN=128, BK=64; 256 thr =
// 4 waves (2x2), per-wave 64x64, acc[4][4]=64 VGPR.
// LDS = 2 buffers x 32KB = 64KB -> 2 blocks/CU co-resident; grids 640/368
// blocks -> ALL resident; cross-block overlap is the latency hider (m114).
// BK=64 stored as 2 independent BK=32 subtiles, each in the R4-verified
// conflict-free slot-XOR layout (0 SQ_LDS_BANK_CONFLICT measured).
// Per K-tile: plain ds-reads (compiler emits fine-grained lgkmcnt) ->
// stage(t+1, buf^1) (HBM latency hides under the 32-MFMA burst) ->
// MFMA -> one __syncthreads (its vmcnt(0) drain completes the prefetch).
// MODE 0: bf16 out + bias + fused RoPE. MODE 1: fp32 out + bias (col<N).
template <int MODE>
__global__ __launch_bounds__(256, 2) void gemm_db(const u16* __restrict__ A,
                                                  const u16* __restrict__ Bp,
                                                  const float* __restrict__ bias,
                                                  const float* __restrict__ cosb,
                                                  const float* __restrict__ sinb,
                                                  void* __restrict__ out0,
                                                  int N, int Kst, int nkt) {
  __shared__ u16 lds[32768];  // 64KB: buf b at b*32KB; within buf:
                              // A-sub0 @0, A-sub1 @8K, B-sub0 @16K, B-sub1 @24K
  const int tid = threadIdx.x, lane = tid & 63, wid = tid >> 6;
  const int wm = wid >> 1, wn = wid & 1;
  const int lr = lane & 15, lk = lane >> 4;

  // T1: bijective XCD swizzle over (x,y)
  const int gm = gridDim.x;
  int nwg = gm * gridDim.y;
  int bid = blockIdx.y * gm + blockIdx.x;
  int q8 = nwg >> 3, r8 = nwg & 7;
  int xcd = bid & 7, seq = bid >> 3;
  int swz = (xcd < r8 ? xcd * (q8 + 1) : r8 * (q8 + 1) + (xcd - r8) * q8) + seq;
  const long brow = (long)(swz % gm) * 128;
  const long bcol = (long)(swz / gm) * 128;

  char* L = (char*)lds;
  // staging sources: chunk c = tid + 256*i -> subtile row c>>2, phys slot
  // c&3; source k-chunk = (c&3) ^ ((c>>3)&3)  [= same for both i since
  // 256*i shifts row by 64 (mod-4-invariant)]. Per thread: 8 loads.
  const int kc8 = ((tid & 3) ^ ((tid >> 3) & 3)) * 8;
  const u16* As[2];
  const u16* Bs[2];
#pragma unroll
  for (int i = 0; i < 2; ++i) {
    int c = tid + 256 * i;
    As[i] = A  + (brow + (c >> 2)) * (long)Kst + kc8;
    Bs[i] = Bp + (bcol + (c >> 2)) * (long)Kst + kc8;
  }
  auto stage = [&](int kt, int b) {
    char* d = L + b * 32768;
    long ko = (long)kt * 64;
#pragma unroll
    for (int i = 0; i < 2; ++i) {
      async_load16(As[i] + ko,      d +         i * 4096 + tid * 16);
      async_load16(As[i] + ko + 32, d +  8192 + i * 4096 + tid * 16);
      async_load16(Bs[i] + ko,      d + 16384 + i * 4096 + tid * 16);
      async_load16(Bs[i] + ko + 32, d + 24576 + i * 4096 + tid * 16);
    }
  };

  // fragment reads: row*64B + phys16, phys = lk ^ ((lr>>1)&3) (0-conflict)
  const int phys = (lk ^ ((lr >> 1) & 3)) << 4;
  const int arow = (wm * 64 + lr) * 64 + phys;  // + m*1024 + kc*8192
  const int brow_ = (wn * 64 + lr) * 64 + phys; // + n*1024 + kc*8192 + 16384

  f32x4 acc[4][4] = {};
  stage(0, 0);
  __syncthreads();

  for (int t = 0; t < nkt; ++t) {
    const char* Lb = L + (t & 1) * 32768;
    bf16x8 a0[4], b0[4], a1[4], b1[4];
#pragma unroll
    for (int m = 0; m < 4; ++m) a0[m] = *(const bf16x8*)(Lb + arow + m * 1024);
#pragma unroll
    for (int n = 0; n < 4; ++n) b0[n] = *(const bf16x8*)(Lb + 16384 + brow_ + n * 1024);
#pragma unroll
    for (int m = 0; m < 4; ++m) a1[m] = *(const bf16x8*)(Lb + 8192 + arow + m * 1024);
#pragma unroll
    for (int n = 0; n < 4; ++n) b1[n] = *(const bf16x8*)(Lb + 24576 + brow_ + n * 1024);
    if (t + 1 < nkt) stage(t + 1, (t & 1) ^ 1);   // hides under MFMA below
#pragma unroll
    for (int m = 0; m < 4; ++m)
#pragma unroll
      for (int n = 0; n < 4; ++n)
        acc[m][n] = __builtin_amdgcn_mfma_f32_16x16x32_bf16(a0[m], b0[n], acc[m][n], 0, 0, 0);
#pragma unroll
    for (int m = 0; m < 4; ++m)
#pragma unroll
      for (int n = 0; n < 4; ++n)
        acc[m][n] = __builtin_amdgcn_mfma_f32_16x16x32_bf16(a1[m], b1[n], acc[m][n], 0, 0, 0);
    __syncthreads();  // drains prefetch (vmcnt0) + closes WAR for next stage
  }

  // ---- epilogue ----
  const int col0 = (int)bcol + wn * 64;  // wave-uniform head base (64-aligned)
  if (MODE == 0) {
    const bool rope = (col0 < 4608);  // q or k head
#pragma unroll
    for (int mf = 0; mf < 4; ++mf) {
      long row = brow + wm * 64 + mf * 16 + lk * 4;
#pragma unroll
      for (int r = 0; r < 4; ++r) {
        long s = row + r;
        if (rope) {
#pragma unroll
          for (int nf = 0; nf < 2; ++nf) {
            int col = col0 + nf * 16 + lr;
            int d = nf * 16 + lr;                 // 0..31 within head
            float c = cosb[s * 64 + d], sn = sinb[s * 64 + d];
            float x1 = acc[mf][nf][r] + bias[col];
            float x2 = acc[mf][nf + 2][r] + bias[col + 32];
            ((u16*)out0)[s * (long)N + col]      = f2bf(x1 * c - x2 * sn);
            ((u16*)out0)[s * (long)N + col + 32] = f2bf(x2 * c + x1 * sn);
          }
        } else {
#pragma unroll
          for (int nf = 0; nf < 4; ++nf) {
            int col = col0 + nf * 16 + lr;
            ((u16*)out0)[s * (long)N + col] = f2bf(acc[mf][nf][r] + bias[col]);
          }
        }
      }
    }
  } else {
#pragma unroll
    for (int mf = 0; mf < 4; ++mf) {
      long row = brow + wm * 64 + mf * 16 + lk * 4;
#pragma unroll
      for (int nf = 0; nf < 4; ++nf) {
        int col = col0 + nf * 16 + lr;
        if (col < N) {
          float bv = bias[col];
#pragma unroll
          for (int r = 0; r < 4; ++r)
            ((float*)out0)[(row + r) * (long)N + col] = acc[mf][nf][r] + bv;
        }
      }
    }
  }
}

// ---- sliding-window attention with sinks (unchanged) ----
__global__ __launch_bounds__(256, 1) void attn_kernel(const u16* __restrict__ QKV,
                                                      const float* __restrict__ sinks,
                                                      u16* __restrict__ Oa) {
  __shared__ u16 Ks[64 * 64];
  __shared__ u16 Vt[64 * 64];
  __shared__ u16 Ps[4][64 * 72];
  const int tid = threadIdx.x, wid = tid >> 6, lane = tid & 63;
  const int lr = lane & 15, lk = lane >> 4;
  const int i0 = blockIdx.x * 64;
  const int h = blockIdx.y * 4 + wid;
  const int g = h >> 3;

  bf16x8 qf[4][2];
#pragma unroll
  for (int m = 0; m < 4; ++m)
#pragma unroll
    for (int kc = 0; kc < 2; ++kc)
      qf[m][kc] = *(const bf16x8*)&QKV[(long)(i0 + m * 16 + lr) * NQKV + h * 64 + kc * 32 + lk * 8];

  const float sinkh = sinks[h];
  float mrun[4][4], lrun[4][4];
  f32x4 oacc[4][4] = {};
#pragma unroll
  for (int m = 0; m < 4; ++m)
#pragma unroll
    for (int r = 0; r < 4; ++r) { mrun[m][r] = sinkh; lrun[m][r] = 0.f; }

  const int jb0 = (i0 >= 128) ? (i0 - 128) : 0;
  for (int jb = jb0; jb <= i0; jb += 64) {
#pragma unroll
    for (int i = 0; i < 2; ++i) {
      int c = wid * 128 + i * 64 + lane;
      int row = c >> 3, sp = c & 7;
      int ssrc = sp ^ (row & 7);
      async_load16(QKV + (long)(jb + row) * NQKV + 4096 + g * 64 + ssrc * 8,
                   ((char*)Ks) + c * 16);
    }
    {
      int j0 = (tid & 31) * 2, d0 = (tid >> 5) * 8;
      const u16* vp = QKV + (long)(jb + j0) * NQKV + 4608 + g * 64 + d0;
      int4 rv0 = *(const int4*)vp;
      int4 rv1 = *(const int4*)(vp + NQKV);
      const u16* a0 = (const u16*)&rv0;
      const u16* a1 = (const u16*)&rv1;
#pragma unroll
      for (int e = 0; e < 8; ++e) {
        int d = d0 + e;
        unsigned val = (unsigned)a0[e] | ((unsigned)a1[e] << 16);
        int byt = d * 128 + ((((j0 >> 3) ^ (d & 7)) << 4)) + ((j0 & 7) * 2);
        *(unsigned*)((char*)Vt + byt) = val;
      }
    }
    __syncthreads();

    f32x4 sf[4][4] = {};
    __builtin_amdgcn_s_setprio(1);
#pragma unroll
    for (int kc = 0; kc < 2; ++kc) {
      bf16x8 kf[4];
#pragma unroll
      for (int cf = 0; cf < 4; ++cf) {
        int row = cf * 16 + lr;
        kf[cf] = *(const bf16x8*)((const char*)Ks + row * 128 + (((kc * 4 + lk) ^ (lr & 7)) << 4));
      }
#pragma unroll
      for (int m = 0; m < 4; ++m)
#pragma unroll
        for (int cf = 0; cf < 4; ++cf)
          sf[m][cf] = __builtin_amdgcn_mfma_f32_16x16x32_bf16(qf[m][kc], kf[cf], sf[m][cf], 0, 0, 0);
    }
    __builtin_amdgcn_s_setprio(0);

#pragma unroll
    for (int m = 0; m < 4; ++m) {
      float rmax[4];
#pragma unroll
      for (int r = 0; r < 4; ++r) {
        int i = i0 + m * 16 + lk * 4 + r;
        float mx = NEG_INF;
#pragma unroll
        for (int cf = 0; cf < 4; ++cf) {
          int j = jb + cf * 16 + lr;
          float v = sf[m][cf][r] * SCALE;
          bool ok = (j <= i) && (j > i - 128);
          v = ok ? v : NEG_INF;
          sf[m][cf][r] = v;
          mx = fmaxf(mx, v);
        }
#pragma unroll
        for (int off = 1; off < 16; off <<= 1) mx = fmaxf(mx, __shfl_xor(mx, off, 64));
        rmax[r] = mx;
      }
#pragma unroll
      for (int r = 0; r < 4; ++r) {
        float mnew = fmaxf(mrun[m][r], rmax[r]);
        float corr = __expf(mrun[m][r] - mnew);
        mrun[m][r] = mnew;
        float rsum = 0.f;
#pragma unroll
        for (int cf = 0; cf < 4; ++cf) {
          float p = __expf(sf[m][cf][r] - mnew);
          sf[m][cf][r] = p;
          rsum += p;
        }
#pragma unroll
        for (int off = 1; off < 16; off <<= 1) rsum += __shfl_xor(rsum, off, 64);
        lrun[m][r] = lrun[m][r] * corr + rsum;
#pragma unroll
        for (int dn = 0; dn < 4; ++dn) oacc[m][dn][r] *= corr;
      }
    }

#pragma unroll
    for (int m = 0; m < 4; ++m)
#pragma unroll
      for (int cf = 0; cf < 4; ++cf)
#pragma unroll
        for (int r = 0; r < 4; ++r)
          Ps[wid][(m * 16 + lk * 4 + r) * 72 + cf * 16 + lr] = f2bf(sf[m][cf][r]);
    __syncthreads();

    __builtin_amdgcn_s_setprio(1);
#pragma unroll
    for (int kc = 0; kc < 2; ++kc) {
      bf16x8 pf[4], vf[4];
#pragma unroll
      for (int m = 0; m < 4; ++m)
        pf[m] = *(const bf16x8*)&Ps[wid][(m * 16 + lr) * 72 + kc * 32 + lk * 8];
#pragma unroll
      for (int dn = 0; dn < 4; ++dn) {
        int row = dn * 16 + lr;
        vf[dn] = *(const bf16x8*)((const char*)Vt + row * 128 + (((kc * 4 + lk) ^ (lr & 7)) << 4));
      }
#pragma unroll
      for (int m = 0; m < 4; ++m)
#pragma unroll
        for (int dn = 0; dn < 4; ++dn)
          oacc[m][dn] = __builtin_amdgcn_mfma_f32_16x16x32_bf16(pf[m], vf[dn], oacc[m][dn], 0, 0, 0);
    }
    __builtin_amdgcn_s_setprio(0);
    __syncthreads();
  }

#pragma unroll
  for (int m = 0; m < 4; ++m)
#pragma unroll
    for (int r = 0; r < 4; ++r) {
      float denom = lrun[m][r] + __expf(sinkh - mrun[m][r]);
      float inv = 1.f / denom;
      long row = i0 + m * 16 + lk * 4 + r;
#pragma unroll
      for (int dn = 0; dn < 4; ++dn)
        Oa[row * 4096 + h * 64 + dn * 16 + lr] = f2bf(oacc[m][dn][r] * inv);
    }
}

extern "C" void kernel_launch(void* const* d_in, const int* in_sizes, int n_in,
                              void* d_out, int out_size, void* d_ws, size_t ws_size,
                              hipStream_t stream) {
  const float* X    = (const float*)d_in[0];
  const float* cosb = (const float*)d_in[1];
  const float* sinb = (const float*)d_in[2];
  const float* Wq   = (const float*)d_in[3];
  const float* bq   = (const float*)d_in[4];
  const float* Wk   = (const float*)d_in[5];
  const float* bk   = (const float*)d_in[6];
  const float* Wv   = (const float*)d_in[7];
  const float* bv   = (const float*)d_in[8];
  const float* Wo   = (const float*)d_in[9];
  const float* bo   = (const float*)d_in[10];
  const float* sinks = (const float*)d_in[11];

  char* ws = (char*)d_ws;
  size_t off = 0;
  auto alloc = [&](size_t bytes) -> void* {
    void* p = ws + off;
    off += (bytes + 255) & ~(size_t)255;
    return p;
  };
  u16*   Xb    = (u16*)alloc((size_t)SEQ * HIDN * 2);            // [2048][2880]
  u16*   Wqkv  = (u16*)alloc((size_t)NQKV * HIDN * 2);           // [5120][2880]
  u16*   Wot   = (u16*)alloc((size_t)2944 * 4096 * 2);           // [2944][4096] (pad rows)
  float* bqkv  = (float*)alloc((size_t)NQKV * 4);
  u16*   QKV   = (u16*)alloc((size_t)SEQ * NQKV * 2);            // [2048][5120]
  u16*   Ab    = (u16*)alloc((size_t)SEQ * 4096 * 2);            // attn out [2048][4096]
  (void)ws_size; (void)in_sizes; (void)n_in; (void)out_size;

  conv_f2b<<<(SEQ * HIDN / 4 + 255) / 256, 256, 0, stream>>>(X, Xb, (long)SEQ * HIDN / 4);
  transpose_qkv<<<dim3(NQKV / 32, HIDN / 32), 256, 0, stream>>>(Wq, Wk, Wv, Wqkv);
  transpose_f2b<<<dim3(HIDN / 32, 4096 / 32), 256, 0, stream>>>(Wo, Wot, 4096, HIDN, 4096);
  concat_bias<<<(NQKV + 255) / 256, 256, 0, stream>>>(bq, bk, bv, bqkv);
  // QKV projection (+bias +fused RoPE): [2048][2880] @ [5120][2880]^T -> bf16
  gemm_db<0><<<dim3(16, 40), 256, 0, stream>>>(Xb, Wqkv, bqkv, cosb, sinb,
                                               QKV, NQKV, HIDN, 45);
  // sliding-window attention with sinks
  attn_kernel<<<dim3(SEQ / 64, 64 / 4), 256, 0, stream>>>(QKV, sinks, Ab);
  // O-proj (+bo): [2048][4096] @ [2944pad][4096]^T -> fp32 [2048][2880]
  gemm_db<1><<<dim3(16, 23), 256, 0, stream>>>(Ab, Wot, bo, nullptr, nullptr,
                                               d_out, HIDN, 4096, 64);
}

// Round 10
// 253.667 us; speedup vs baseline: 1.0422x; 1.0422x over previous
//
#include <hip/hip_runtime.h>

typedef unsigned short u16;
typedef __bf16 bf16x8 __attribute__((ext_vector_type(8)));
typedef float f32x4 __attribute__((ext_vector_type(4)));

// ---- problem constants ----
constexpr int SEQ = 2048;
constexpr int HIDN = 2880;
constexpr int NQKV = 5120;   // 4096 q | 512 k | 512 v
constexpr float SCALE = 0.125f;   // 1/sqrt(64)
constexpr float NEG_INF = -1e30f;
constexpr int BUFSTRIDE = 24576;  // 24KB per GEMM LDS buffer (A 16KB | B 8KB)

__device__ __forceinline__ u16 f2bf(float f) {
  unsigned int u = __builtin_bit_cast(unsigned int, f);
  u += 0x7FFFu + ((u >> 16) & 1u);
  return (u16)(u >> 16);
}
__device__ __forceinline__ float bf2f(u16 h) {
  unsigned int u = ((unsigned int)h) << 16;
  return __builtin_bit_cast(float, u);
}
__device__ __forceinline__ void async_load16(const void* g, void* l) {
  __builtin_amdgcn_global_load_lds(
      (const __attribute__((address_space(1))) unsigned int*)g,
      (__attribute__((address_space(3))) unsigned int*)l, 16, 0, 0);
}

// ---- fp32 -> bf16 flat convert ----
__global__ __launch_bounds__(256) void conv_f2b(const float* __restrict__ in,
                                                u16* __restrict__ out, long n4) {
  long i = (long)blockIdx.x * 256 + threadIdx.x;
  if (i >= n4) return;
  float4 v = ((const float4*)in)[i];
  u16 o0 = f2bf(v.x), o1 = f2bf(v.y), o2 = f2bf(v.z), o3 = f2bf(v.w);
  out[i * 4 + 0] = o0; out[i * 4 + 1] = o1; out[i * 4 + 2] = o2; out[i * 4 + 3] = o3;
}

// ---- merged Wq|Wk|Wv transpose-convert -> Wqkv[5120][2880] bf16 ----
__global__ __launch_bounds__(256) void transpose_qkv(const float* __restrict__ Wq,
                                                     const float* __restrict__ Wk,
                                                     const float* __restrict__ Wv,
                                                     u16* __restrict__ out) {
  __shared__ float tile[32][33];
  int c0 = blockIdx.x * 32, r0 = blockIdx.y * 32;   // c0: qkv col, r0: hid row
  int tx = threadIdx.x & 31, ty = threadIdx.x >> 5;
  const float* src; int C, cl;
  if (c0 < 4096)      { src = Wq; C = 4096; cl = c0; }
  else if (c0 < 4608) { src = Wk; C = 512;  cl = c0 - 4096; }
  else                { src = Wv; C = 512;  cl = c0 - 4608; }
#pragma unroll
  for (int i = 0; i < 32; i += 8)
    tile[ty + i][tx] = src[(long)(r0 + ty + i) * C + cl + tx];
  __syncthreads();
#pragma unroll
  for (int i = 0; i < 32; i += 8)
    out[(long)(c0 + ty + i) * HIDN + r0 + tx] = f2bf(tile[tx][ty + i]);
}

// ---- fp32 [R][C] -> bf16 out[c][r] (transpose-convert), dims % 32 == 0 ----
__global__ __launch_bounds__(256) void transpose_f2b(const float* __restrict__ in,
                                                     u16* __restrict__ out,
                                                     int R, int C, int ostride) {
  __shared__ float tile[32][33];
  int c0 = blockIdx.x * 32, r0 = blockIdx.y * 32;
  int tx = threadIdx.x & 31, ty = threadIdx.x >> 5;
#pragma unroll
  for (int i = 0; i < 32; i += 8)
    tile[ty + i][tx] = in[(long)(r0 + ty + i) * C + c0 + tx];
  __syncthreads();
#pragma unroll
  for (int i = 0; i < 32; i += 8)
    out[(long)(c0 + ty + i) * ostride + r0 + tx] = f2bf(tile[tx][ty + i]);
}

__global__ __launch_bounds__(256) void concat_bias(const float* bq, const float* bk,
                                                   const float* bv, float* out) {
  int t = blockIdx.x * 256 + threadIdx.x;
  if (t < 4096) out[t] = bq[t];
  else if (t < 4608) out[t] = bk[t - 4096];
  else if (t < 5120) out[t] = bv[t - 4608];
}

// ======== GEMM: C[M][N] = A[M][K] @ B_t[N][K]^T ========
// BM=256, BN=128, BK=32; 256 thr = 4 waves (2M x 2N), per-wave 128x64 ->
// LDS traffic 12KB/wave/tile (48KB per 24KB tile) = 0.023 B/FLOP, below the
// ds_read_b128 (85 B/cyc) vs MFMA (3378 F/cyc) balance; the 64x64-wave
// configs sit above it (their ~40-50% ceiling). Double-buffered 48KB LDS ->
// 2 blocks/CU; plain loop {reads -> stage(t+1) -> 32 MFMA -> syncthreads}:
// sync's vmcnt(0) drain lands the prefetch; cross-block waves hide stage
// latency (m114). Slot-XOR LDS layout (verified 0-conflict in R4/R9).
// MODE 0: bf16 out + bias + fused RoPE. MODE 1: fp32 split-K partial.
template <int MODE>
__global__ __launch_bounds__(256, 2) void gemm_v10(const u16* __restrict__ A,
                                                   const u16* __restrict__ Bp,
                                                   const float* __restrict__ bias,
                                                   const float* __restrict__ cosb,
                                                   const float* __restrict__ sinb,
                                                   void* __restrict__ out0,
                                                   float* __restrict__ out1,
                                                   int N, int Kst, int nkt) {
  __shared__ u16 lds[24576];  // 48KB total: buf b at b*24KB; A @0, B @16KB
  const int tid = threadIdx.x, lane = tid & 63, wid = tid >> 6;
  const int wm = wid >> 1, wn = wid & 1;
  const int lr = lane & 15, lk = lane >> 4;

  // T1: bijective XCD swizzle over (x,y)
  const int gm = gridDim.x;
  int nwg = gm * gridDim.y;
  int bid = blockIdx.y * gm + blockIdx.x;
  int q8 = nwg >> 3, r8 = nwg & 7;
  int xcd = bid & 7, seq = bid >> 3;
  int swz = (xcd < r8 ? xcd * (q8 + 1) : r8 * (q8 + 1) + (xcd - r8) * q8) + seq;
  const long brow = (long)(swz % gm) * 256;
  const long bcol = (long)(swz / gm) * 128;
  const long kbase = (MODE == 1) ? (long)blockIdx.z * nkt * 32 : 0;

  char* L = (char*)lds;
  // staging: chunk c -> row c>>2, phys slot c&3; source k pre-swizzled:
  // slot s of row r holds source k-chunk s ^ ((r>>1)&3) = (c&3)^((c>>3)&3)
  const int kc8 = ((tid & 3) ^ ((tid >> 3) & 3)) * 8;  // invariant under c+=256
  const u16* As[4];
  const u16* Bs[2];
#pragma unroll
  for (int i = 0; i < 4; ++i)
    As[i] = A + (brow + ((tid + 256 * i) >> 2)) * (long)Kst + kbase + kc8;
#pragma unroll
  for (int i = 0; i < 2; ++i)
    Bs[i] = Bp + (bcol + ((tid + 256 * i) >> 2)) * (long)Kst + kbase + kc8;
  auto stage = [&](int kt, int b) {   // 6 loads/thread
    char* d = L + b * BUFSTRIDE;
    long ko = (long)kt * 32;
#pragma unroll
    for (int i = 0; i < 4; ++i)
      async_load16(As[i] + ko, d + (tid + 256 * i) * 16);
#pragma unroll
    for (int i = 0; i < 2; ++i)
      async_load16(Bs[i] + ko, d + 16384 + (tid + 256 * i) * 16);
  };

  // fragment reads: row*64B + phys16, phys = lk ^ ((lr>>1)&3)
  const int phys = (lk ^ ((lr >> 1) & 3)) << 4;
  const int arow = (wm * 128 + lr) * 64 + phys;          // + m*1024
  const int brw  = 16384 + (wn * 64 + lr) * 64 + phys;   // + n*1024

  f32x4 acc[8][4] = {};
  stage(0, 0);
  __syncthreads();

  for (int t = 0; t < nkt; ++t) {
    const char* Lb = L + (t & 1) * BUFSTRIDE;
    bf16x8 a[8], b[4];
#pragma unroll
    for (int m = 0; m < 8; ++m) a[m] = *(const bf16x8*)(Lb + arow + m * 1024);
#pragma unroll
    for (int n = 0; n < 4; ++n) b[n] = *(const bf16x8*)(Lb + brw + n * 1024);
    if (t + 1 < nkt) stage(t + 1, (t & 1) ^ 1);   // hides under MFMA below
#pragma unroll
    for (int m = 0; m < 8; ++m)
#pragma unroll
      for (int n = 0; n < 4; ++n)
        acc[m][n] = __builtin_amdgcn_mfma_f32_16x16x32_bf16(a[m], b[n], acc[m][n], 0, 0, 0);
    __syncthreads();  // vmcnt(0) drain lands prefetch; closes WAR
  }

  // ---- epilogue ----
  const int col0 = (int)bcol + wn * 64;  // wave-uniform head base (64-aligned)
  if (MODE == 0) {
    const bool rope = (col0 < 4608);  // q or k head
#pragma unroll
    for (int mf = 0; mf < 8; ++mf) {
      long row = brow + wm * 128 + mf * 16 + lk * 4;
#pragma unroll
      for (int r = 0; r < 4; ++r) {
        long s = row + r;
        if (rope) {
#pragma unroll
          for (int nf = 0; nf < 2; ++nf) {
            int col = col0 + nf * 16 + lr;
            int d = nf * 16 + lr;                 // 0..31 within head
            float c = cosb[s * 64 + d], sn = sinb[s * 64 + d];
            float x1 = acc[mf][nf][r] + bias[col];
            float x2 = acc[mf][nf + 2][r] + bias[col + 32];
            ((u16*)out0)[s * (long)N + col]      = f2bf(x1 * c - x2 * sn);
            ((u16*)out0)[s * (long)N + col + 32] = f2bf(x2 * c + x1 * sn);
          }
        } else {
#pragma unroll
          for (int nf = 0; nf < 4; ++nf) {
            int col = col0 + nf * 16 + lr;
            ((u16*)out0)[s * (long)N + col] = f2bf(acc[mf][nf][r] + bias[col]);
          }
        }
      }
    }
  } else {
    float* o = (blockIdx.z == 0) ? (float*)out0 : out1;
#pragma unroll
    for (int mf = 0; mf < 8; ++mf) {
      long row = brow + wm * 128 + mf * 16 + lk * 4;
#pragma unroll
      for (int nf = 0; nf < 4; ++nf) {
        int col = col0 + nf * 16 + lr;
        if (col < N) {
#pragma unroll
          for (int r = 0; r < 4; ++r)
            o[(row + r) * (long)N + col] = acc[mf][nf][r];
        }
      }
    }
  }
}

// ---- combine split-K partials: out = out + P1 + bias ----
__global__ __launch_bounds__(256) void combine_out(const float* __restrict__ P1,
                                                   const float* __restrict__ bias,
                                                   float* __restrict__ out) {
  long i = (long)blockIdx.x * 256 + threadIdx.x;
  if (i >= (long)SEQ * HIDN / 4) return;
  int c4 = (int)(i % (HIDN / 4));
  float4 p0 = ((const float4*)out)[i];
  float4 p1 = ((const float4*)P1)[i];
  float4 b = ((const float4*)bias)[c4];
  float4 r;
  r.x = p0.x + p1.x + b.x; r.y = p0.y + p1.y + b.y;
  r.z = p0.z + p1.z + b.z; r.w = p0.w + p1.w + b.w;
  ((float4*)out)[i] = r;
}

// ---- sliding-window attention with sinks (unchanged) ----
__global__ __launch_bounds__(256, 1) void attn_kernel(const u16* __restrict__ QKV,
                                                      const float* __restrict__ sinks,
                                                      u16* __restrict__ Oa) {
  __shared__ u16 Ks[64 * 64];
  __shared__ u16 Vt[64 * 64];
  __shared__ u16 Ps[4][64 * 72];
  const int tid = threadIdx.x, wid = tid >> 6, lane = tid & 63;
  const int lr = lane & 15, lk = lane >> 4;
  const int i0 = blockIdx.x * 64;
  const int h = blockIdx.y * 4 + wid;
  const int g = h >> 3;

  bf16x8 qf[4][2];
#pragma unroll
  for (int m = 0; m < 4; ++m)
#pragma unroll
    for (int kc = 0; kc < 2; ++kc)
      qf[m][kc] = *(const bf16x8*)&QKV[(long)(i0 + m * 16 + lr) * NQKV + h * 64 + kc * 32 + lk * 8];

  const float sinkh = sinks[h];
  float mrun[4][4], lrun[4][4];
  f32x4 oacc[4][4] = {};
#pragma unroll
  for (int m = 0; m < 4; ++m)
#pragma unroll
    for (int r = 0; r < 4; ++r) { mrun[m][r] = sinkh; lrun[m][r] = 0.f; }

  const int jb0 = (i0 >= 128) ? (i0 - 128) : 0;
  for (int jb = jb0; jb <= i0; jb += 64) {
#pragma unroll
    for (int i = 0; i < 2; ++i) {
      int c = wid * 128 + i * 64 + lane;
      int row = c >> 3, sp = c & 7;
      int ssrc = sp ^ (row & 7);
      async_load16(QKV + (long)(jb + row) * NQKV + 4096 + g * 64 + ssrc * 8,
                   ((char*)Ks) + c * 16);
    }
    {
      int j0 = (tid & 31) * 2, d0 = (tid >> 5) * 8;
      const u16* vp = QKV + (long)(jb + j0) * NQKV + 4608 + g * 64 + d0;
      int4 rv0 = *(const int4*)vp;
      int4 rv1 = *(const int4*)(vp + NQKV);
      const u16* a0 = (const u16*)&rv0;
      const u16* a1 = (const u16*)&rv1;
#pragma unroll
      for (int e = 0; e < 8; ++e) {
        int d = d0 + e;
        unsigned val = (unsigned)a0[e] | ((unsigned)a1[e] << 16);
        int byt = d * 128 + ((((j0 >> 3) ^ (d & 7)) << 4)) + ((j0 & 7) * 2);
        *(unsigned*)((char*)Vt + byt) = val;
      }
    }
    __syncthreads();

    f32x4 sf[4][4] = {};
    __builtin_amdgcn_s_setprio(1);
#pragma unroll
    for (int kc = 0; kc < 2; ++kc) {
      bf16x8 kf[4];
#pragma unroll
      for (int cf = 0; cf < 4; ++cf) {
        int row = cf * 16 + lr;
        kf[cf] = *(const bf16x8*)((const char*)Ks + row * 128 + (((kc * 4 + lk) ^ (lr & 7)) << 4));
      }
#pragma unroll
      for (int m = 0; m < 4; ++m)
#pragma unroll
        for (int cf = 0; cf < 4; ++cf)
          sf[m][cf] = __builtin_amdgcn_mfma_f32_16x16x32_bf16(qf[m][kc], kf[cf], sf[m][cf], 0, 0, 0);
    }
    __builtin_amdgcn_s_setprio(0);

#pragma unroll
    for (int m = 0; m < 4; ++m) {
      float rmax[4];
#pragma unroll
      for (int r = 0; r < 4; ++r) {
        int i = i0 + m * 16 + lk * 4 + r;
        float mx = NEG_INF;
#pragma unroll
        for (int cf = 0; cf < 4; ++cf) {
          int j = jb + cf * 16 + lr;
          float v = sf[m][cf][r] * SCALE;
          bool ok = (j <= i) && (j > i - 128);
          v = ok ? v : NEG_INF;
          sf[m][cf][r] = v;
          mx = fmaxf(mx, v);
        }
#pragma unroll
        for (int off = 1; off < 16; off <<= 1) mx = fmaxf(mx, __shfl_xor(mx, off, 64));
        rmax[r] = mx;
      }
#pragma unroll
      for (int r = 0; r < 4; ++r) {
        float mnew = fmaxf(mrun[m][r], rmax[r]);
        float corr = __expf(mrun[m][r] - mnew);
        mrun[m][r] = mnew;
        float rsum = 0.f;
#pragma unroll
        for (int cf = 0; cf < 4; ++cf) {
          float p = __expf(sf[m][cf][r] - mnew);
          sf[m][cf][r] = p;
          rsum += p;
        }
#pragma unroll
        for (int off = 1; off < 16; off <<= 1) rsum += __shfl_xor(rsum, off, 64);
        lrun[m][r] = lrun[m][r] * corr + rsum;
#pragma unroll
        for (int dn = 0; dn < 4; ++dn) oacc[m][dn][r] *= corr;
      }
    }

#pragma unroll
    for (int m = 0; m < 4; ++m)
#pragma unroll
      for (int cf = 0; cf < 4; ++cf)
#pragma unroll
        for (int r = 0; r < 4; ++r)
          Ps[wid][(m * 16 + lk * 4 + r) * 72 + cf * 16 + lr] = f2bf(sf[m][cf][r]);
    __syncthreads();

    __builtin_amdgcn_s_setprio(1);
#pragma unroll
    for (int kc = 0; kc < 2; ++kc) {
      bf16x8 pf[4], vf[4];
#pragma unroll
      for (int m = 0; m < 4; ++m)
        pf[m] = *(const bf16x8*)&Ps[wid][(m * 16 + lr) * 72 + kc * 32 + lk * 8];
#pragma unroll
      for (int dn = 0; dn < 4; ++dn) {
        int row = dn * 16 + lr;
        vf[dn] = *(const bf16x8*)((const char*)Vt + row * 128 + (((kc * 4 + lk) ^ (lr & 7)) << 4));
      }
#pragma unroll
      for (int m = 0; m < 4; ++m)
#pragma unroll
        for (int dn = 0; dn < 4; ++dn)
          oacc[m][dn] = __builtin_amdgcn_mfma_f32_16x16x32_bf16(pf[m], vf[dn], oacc[m][dn], 0, 0, 0);
    }
    __builtin_amdgcn_s_setprio(0);
    __syncthreads();
  }

#pragma unroll
  for (int m = 0; m < 4; ++m)
#pragma unroll
    for (int r = 0; r < 4; ++r) {
      float denom = lrun[m][r] + __expf(sinkh - mrun[m][r]);
      float inv = 1.f / denom;
      long row = i0 + m * 16 + lk * 4 + r;
#pragma unroll
      for (int dn = 0; dn < 4; ++dn)
        Oa[row * 4096 + h * 64 + dn * 16 + lr] = f2bf(oacc[m][dn][r] * inv);
    }
}

extern "C" void kernel_launch(void* const* d_in, const int* in_sizes, int n_in,
                              void* d_out, int out_size, void* d_ws, size_t ws_size,
                              hipStream_t stream) {
  const float* X    = (const float*)d_in[0];
  const float* cosb = (const float*)d_in[1];
  const float* sinb = (const float*)d_in[2];
  const float* Wq   = (const float*)d_in[3];
  const float* bq   = (const float*)d_in[4];
  const float* Wk   = (const float*)d_in[5];
  const float* bk   = (const float*)d_in[6];
  const float* Wv   = (const float*)d_in[7];
  const float* bv   = (const float*)d_in[8];
  const float* Wo   = (const float*)d_in[9];
  const float* bo   = (const float*)d_in[10];
  const float* sinks = (const float*)d_in[11];

  char* ws = (char*)d_ws;
  size_t off = 0;
  auto alloc = [&](size_t bytes) -> void* {
    void* p = ws + off;
    off += (bytes + 255) & ~(size_t)255;
    return p;
  };
  u16*   Xb    = (u16*)alloc((size_t)SEQ * HIDN * 2);            // [2048][2880]
  u16*   Wqkv  = (u16*)alloc((size_t)NQKV * HIDN * 2);           // [5120][2880]
  u16*   Wot   = (u16*)alloc((size_t)2944 * 4096 * 2);           // [2944][4096] (pad rows)
  float* bqkv  = (float*)alloc((size_t)NQKV * 4);
  u16*   QKV   = (u16*)alloc((size_t)SEQ * NQKV * 2);            // [2048][5120]
  u16*   Ab    = (u16*)alloc((size_t)SEQ * 4096 * 2);            // attn out [2048][4096]
  // split-K partial 1 reuses Wqkv scratch (29.5MB >= 23.6MB; dead after QKV)
  float* Pt1 = (float*)Wqkv;
  (void)ws_size; (void)in_sizes; (void)n_in; (void)out_size;

  conv_f2b<<<(SEQ * HIDN / 4 + 255) / 256, 256, 0, stream>>>(X, Xb, (long)SEQ * HIDN / 4);
  transpose_qkv<<<dim3(NQKV / 32, HIDN / 32), 256, 0, stream>>>(Wq, Wk, Wv, Wqkv);
  transpose_f2b<<<dim3(HIDN / 32, 4096 / 32), 256, 0, stream>>>(Wo, Wot, 4096, HIDN, 4096);
  concat_bias<<<(NQKV + 255) / 256, 256, 0, stream>>>(bq, bk, bv, bqkv);
  // QKV projection (+bias +fused RoPE): [2048][2880] @ [5120][2880]^T -> bf16
  gemm_v10<0><<<dim3(8, 40, 1), 256, 0, stream>>>(Xb, Wqkv, bqkv, cosb, sinb,
                                                  QKV, nullptr, NQKV, HIDN, 90);
  // sliding-window attention with sinks
  attn_kernel<<<dim3(SEQ / 64, 64 / 4), 256, 0, stream>>>(QKV, sinks, Ab);
  // O-proj: [2048][4096] @ [2944pad][4096]^T, split-K x2 -> fp32 partials
  gemm_v10<1><<<dim3(8, 23, 2), 256, 0, stream>>>(Ab, Wot, nullptr, nullptr, nullptr,
                                                  d_out, Pt1, HIDN, 4096, 64);
  combine_out<<<(SEQ * HIDN / 4 + 255) / 256, 256, 0, stream>>>(Pt1, bo, (float*)d_out);
}